// Round 2
// baseline (1294.776 us; speedup 1.0000x reference)
//
#include <hip/hip_runtime.h>
#include <hip/hip_bf16.h>
#include <math.h>

// Problem constants (from reference)
#define N_NODES 50000
#define N_EDGES 800000
#define EF      (N_EDGES + N_NODES)   // edges + self loops = 850000
#define NEG     0.2f

// Workspace layout (in 4-byte words)
#define OFF_LOOP   0          // loop_attr: N*16 floats
#define OFF_CNT    800000     // cnt: N ints (in-degree, real edges only)
#define OFF_ROWPTR 850000     // row_ptr: N ints
#define OFF_CURSOR 900000     // cursor: N ints
#define OFF_PART   950000     // scan partials: 256 ints
#define OFF_CSR    950256     // csr_eid: EF ints
#define OFF_XL     1800256    // xl: N*128 floats
#define OFF_XR     8200256    // xr: N*128 floats
#define OFF_LOGIT  14600256   // logit: EF*4 floats
// total = 18,000,256 words = 72.0 MB

#define SCAN_BLOCKS 196       // ceil(50000/256)
#define LNT 8                 // nodes per block in lin/hist kernels
#define EPB 8                 // edges per wave per block in logit kernel

// ---------------------------------------------------------------------------
// In-degree histogram (real edges only). 800k int atomics, L2-resident.
__global__ void hist_cnt_kernel(const int* __restrict__ tgt, int* __restrict__ cnt)
{
    int e = blockIdx.x * 256 + threadIdx.x;
    if (e >= N_EDGES) return;
    atomicAdd(&cnt[tgt[e]], 1);
}

// ---------------------------------------------------------------------------
// CSR build: row_len[n] = cnt[n] + 1 (self loop). 3-kernel exclusive scan.
__global__ void scanA_kernel(const int* __restrict__ cnt, int* __restrict__ rowptr,
                             int* __restrict__ part)
{
    __shared__ int s[256];
    int tid = threadIdx.x;
    int g = blockIdx.x * 256 + tid;
    int v = (g < N_NODES) ? (cnt[g] + 1) : 0;
    s[tid] = v;
    __syncthreads();
    for (int off = 1; off < 256; off <<= 1) {
        int t = (tid >= off) ? s[tid - off] : 0;
        __syncthreads();
        s[tid] += t;
        __syncthreads();
    }
    if (g < N_NODES) rowptr[g] = s[tid] - v;        // block-local exclusive
    if (tid == 255) part[blockIdx.x] = s[255];      // block total
}

__global__ void scanB_kernel(int* __restrict__ part)
{
    __shared__ int s[256];
    int tid = threadIdx.x;
    int v = (tid < SCAN_BLOCKS) ? part[tid] : 0;    // entries >=SCAN_BLOCKS are poison
    s[tid] = v;
    __syncthreads();
    for (int off = 1; off < 256; off <<= 1) {
        int t = (tid >= off) ? s[tid - off] : 0;
        __syncthreads();
        s[tid] += t;
        __syncthreads();
    }
    part[tid] = s[tid] - v;                         // exclusive
}

__global__ void scanC_kernel(int* __restrict__ rowptr, const int* __restrict__ part,
                             int* __restrict__ cursor)
{
    int g = blockIdx.x * 256 + threadIdx.x;
    if (g >= N_NODES) return;
    int r = rowptr[g] + part[blockIdx.x];
    rowptr[g] = r;
    cursor[g] = r;
}

__global__ void scatter_kernel(const int* __restrict__ tgt, int* __restrict__ cursor,
                               int* __restrict__ csr)
{
    int e = blockIdx.x * 256 + threadIdx.x;
    if (e >= EF) return;
    int t = (e < N_EDGES) ? tgt[e] : (e - N_EDGES);
    int pos = atomicAdd(&cursor[t], 1);
    csr[pos] = e;
}

// ---------------------------------------------------------------------------
// Self-loop attr via CSR gather (no float atomics, deterministic):
// loop_attr[n] = mean of ea over incoming real edges. One wave per node,
// 16 lanes = 16 channels, 4 edges in flight.
__global__ __launch_bounds__(256) void loop_gather_kernel(
    const float* __restrict__ ea, const int* __restrict__ csr,
    const int* __restrict__ rowptr, const int* __restrict__ cnt,
    float* __restrict__ loop_attr)
{
    int wave = threadIdx.x >> 6, lane = threadIdx.x & 63;
    int n = blockIdx.x * 4 + wave;
    if (n >= N_NODES) return;
    int base = rowptr[n];
    int degt = cnt[n] + 1;                   // includes the self-loop slot (skipped below)
    int k = lane & 15;
    float acc = 0.f;
    for (int i = lane >> 4; i < degt; i += 4) {
        int eid = csr[base + i];
        if (eid < N_EDGES) acc += ea[(size_t)eid * 16 + k];
    }
    acc += __shfl_xor(acc, 16);
    acc += __shfl_xor(acc, 32);
    if (lane < 16) {
        int c = cnt[n];
        loop_attr[n * 16 + k] = acc / (float)(c > 0 ? c : 1);
    }
}

// ---------------------------------------------------------------------------
// xl = X@Wl + bl ; xr = X@Wr + br.  128 threads = out channels, LNT nodes/block
// (amortizes weight reads 8x: 6250 blocks * 2*K*128*4B from L2).
template<int K>
__global__ __launch_bounds__(128) void lin_kernel(const float* __restrict__ X,
    const float* __restrict__ Wl, const float* __restrict__ bl,
    const float* __restrict__ Wr, const float* __restrict__ br,
    float* __restrict__ xl, float* __restrict__ xr)
{
    __shared__ float s[LNT][K];
    int j = threadIdx.x;
    int nb = blockIdx.x * LNT;
    for (int t = 0; t < LNT; ++t) {
        int n = nb + t;
        if (n < N_NODES)
            for (int k = j; k < K; k += 128) s[t][k] = X[(size_t)n * K + k];
    }
    __syncthreads();
    float accL[LNT], accR[LNT];
    float blj = bl[j], brj = br[j];
    #pragma unroll
    for (int t = 0; t < LNT; ++t) { accL[t] = blj; accR[t] = brj; }
    for (int k = 0; k < K; ++k) {
        float wl = Wl[k * 128 + j], wr = Wr[k * 128 + j];
        #pragma unroll
        for (int t = 0; t < LNT; ++t) {
            accL[t] = fmaf(s[t][k], wl, accL[t]);
            accR[t] = fmaf(s[t][k], wr, accR[t]);
        }
    }
    for (int t = 0; t < LNT; ++t) {
        int n = nb + t;
        if (n < N_NODES) {
            xl[(size_t)n * 128 + j] = accL[t];
            xr[(size_t)n * 128 + j] = accR[t];
        }
    }
}

// ---------------------------------------------------------------------------
// Per-edge logits: ee = ea_row @ We (on the fly, We in LDS), m = lrelu(xl[s]+xr[t]+ee),
// logit[e,h] = dot(m_h, att_h). One 64-lane wave per edge, 2 channels/lane.
__global__ __launch_bounds__(256) void logit_kernel(const float* __restrict__ xl,
    const float* __restrict__ xr, const float* __restrict__ ea,
    const float* __restrict__ loop_attr, const int* __restrict__ src,
    const int* __restrict__ tgt, const float* __restrict__ We,
    const float* __restrict__ att, float* __restrict__ logit)
{
    __shared__ float sWe[16 * 128];
    __shared__ float sAtt[128];
    int tid = threadIdx.x;
    for (int i = tid; i < 16 * 128; i += 256) sWe[i] = We[i];
    if (tid < 128) sAtt[tid] = att[tid];
    __syncthreads();
    int wave = tid >> 6, lane = tid & 63;
    int c0 = lane * 2;
    float a0 = sAtt[c0], a1 = sAtt[c0 + 1];
    int base = blockIdx.x * (4 * EPB);
    for (int t = 0; t < EPB; ++t) {
        int e = base + t * 4 + wave;
        if (e >= EF) return;                 // wave-uniform, no syncs below
        int s, tg; const float* earow;
        if (e < N_EDGES) { s = src[e]; tg = tgt[e]; earow = ea + (size_t)e * 16; }
        else             { s = e - N_EDGES; tg = s;  earow = loop_attr + (size_t)s * 16; }
        float eav = earow[lane & 15];        // lane L holds ea[L&15]
        float ee0 = 0.f, ee1 = 0.f;
        #pragma unroll
        for (int k = 0; k < 16; ++k) {
            float ak = __shfl(eav, k, 16);
            ee0 = fmaf(ak, sWe[k * 128 + c0], ee0);
            ee1 = fmaf(ak, sWe[k * 128 + c0 + 1], ee1);
        }
        float2 xls = *(const float2*)(xl + (size_t)s * 128 + c0);
        float2 xrt = *(const float2*)(xr + (size_t)tg * 128 + c0);
        float m0 = xls.x + xrt.x + ee0; m0 = (m0 > 0.f) ? m0 : NEG * m0;
        float m1 = xls.y + xrt.y + ee1; m1 = (m1 > 0.f) ? m1 : NEG * m1;
        float part = fmaf(m0, a0, m1 * a1);
        // reduce within 16-lane group = one head (channels h*32..h*32+31)
        part += __shfl_xor(part, 1);
        part += __shfl_xor(part, 2);
        part += __shfl_xor(part, 4);
        part += __shfl_xor(part, 8);
        if ((lane & 15) == 0) logit[(size_t)e * 4 + (lane >> 4)] = part;
    }
}

// ---------------------------------------------------------------------------
// Per-node softmax + aggregation: one 64-lane wave per node, no atomics.
// Pass1: strided max + shuffle reduce. Pass2 (fused): every lane walks every
// edge accumulating den += w and acc += w*xl[src] (den identical across the
// 16-lane head group, so no cross-lane reduce needed); scale by 1/den at end.
__global__ __launch_bounds__(256) void node_kernel(const float* __restrict__ xl,
    const float* __restrict__ logit, const int* __restrict__ csr,
    const int* __restrict__ rowptr, const int* __restrict__ cnt,
    const int* __restrict__ src, const float* __restrict__ bias,
    float* __restrict__ out)
{
    int wave = threadIdx.x >> 6, lane = threadIdx.x & 63;
    int n = blockIdx.x * 4 + wave;
    if (n >= N_NODES) return;
    int base = rowptr[n];
    int deg = cnt[n] + 1;                    // + self loop

    float4 mx = make_float4(-INFINITY, -INFINITY, -INFINITY, -INFINITY);
    for (int i = lane; i < deg; i += 64) {
        int eid = csr[base + i];
        const float4 lg = *(const float4*)(logit + (size_t)eid * 4);
        mx.x = fmaxf(mx.x, lg.x); mx.y = fmaxf(mx.y, lg.y);
        mx.z = fmaxf(mx.z, lg.z); mx.w = fmaxf(mx.w, lg.w);
    }
    for (int m = 1; m < 64; m <<= 1) {
        mx.x = fmaxf(mx.x, __shfl_xor(mx.x, m));
        mx.y = fmaxf(mx.y, __shfl_xor(mx.y, m));
        mx.z = fmaxf(mx.z, __shfl_xor(mx.z, m));
        mx.w = fmaxf(mx.w, __shfl_xor(mx.w, m));
    }
    int h = lane >> 4;
    float mxh = (h == 0) ? mx.x : (h == 1) ? mx.y : (h == 2) ? mx.z : mx.w;
    int c0 = lane * 2;
    float den = 0.f, a0c = 0.f, a1c = 0.f;
    for (int i = 0; i < deg; ++i) {          // all lanes walk edges together
        int eid = csr[base + i];
        int s = (eid < N_EDGES) ? src[eid] : (eid - N_EDGES);
        float w = __expf(logit[(size_t)eid * 4 + h] - mxh);
        den += w;
        float2 v = *(const float2*)(xl + (size_t)s * 128 + c0);
        a0c = fmaf(w, v.x, a0c);
        a1c = fmaf(w, v.y, a1c);
    }
    float rd = 1.0f / den;
    float o0 = fmaxf(fmaf(a0c, rd, bias[c0]), 0.f);   // + bias, ReLU (both convs)
    float o1 = fmaxf(fmaf(a1c, rd, bias[c0 + 1]), 0.f);
    *(float2*)(out + (size_t)n * 128 + c0) = make_float2(o0, o1);
}

// ---------------------------------------------------------------------------
// Final head: io = io @ hw + hb, in place (row-disjoint per block => safe).
__global__ __launch_bounds__(128) void hist_kernel(float* __restrict__ io,
    const float* __restrict__ hw, const float* __restrict__ hb)
{
    __shared__ float s[LNT][128];
    int j = threadIdx.x;
    int nb = blockIdx.x * LNT;
    for (int t = 0; t < LNT; ++t) {
        int n = nb + t;
        if (n < N_NODES) s[t][j] = io[(size_t)n * 128 + j];
    }
    __syncthreads();
    float acc[LNT];
    float b = hb[j];
    #pragma unroll
    for (int t = 0; t < LNT; ++t) acc[t] = b;
    for (int k = 0; k < 128; ++k) {
        float w = hw[k * 128 + j];
        #pragma unroll
        for (int t = 0; t < LNT; ++t) acc[t] = fmaf(s[t][k], w, acc[t]);
    }
    for (int t = 0; t < LNT; ++t) {
        int n = nb + t;
        if (n < N_NODES) io[(size_t)n * 128 + j] = acc[t];
    }
}

// ---------------------------------------------------------------------------
extern "C" void kernel_launch(void* const* d_in, const int* in_sizes, int n_in,
                              void* d_out, int out_size, void* d_ws, size_t ws_size,
                              hipStream_t stream)
{
    const float* x    = (const float*)d_in[0];
    const int*   ei   = (const int*)d_in[1];
    const float* ea   = (const float*)d_in[2];
    const float* w1l  = (const float*)d_in[3];
    const float* b1l  = (const float*)d_in[4];
    const float* w1r  = (const float*)d_in[5];
    const float* b1r  = (const float*)d_in[6];
    const float* w1e  = (const float*)d_in[7];
    const float* att1 = (const float*)d_in[8];
    const float* bias1= (const float*)d_in[9];
    const float* w2l  = (const float*)d_in[10];
    const float* b2l  = (const float*)d_in[11];
    const float* w2r  = (const float*)d_in[12];
    const float* b2r  = (const float*)d_in[13];
    const float* w2e  = (const float*)d_in[14];
    const float* att2 = (const float*)d_in[15];
    const float* bias2= (const float*)d_in[16];
    const float* hw   = (const float*)d_in[17];
    const float* hb   = (const float*)d_in[18];
    const int* src = ei;
    const int* tgt = ei + N_EDGES;

    float* ws        = (float*)d_ws;
    float* loop_attr = ws + OFF_LOOP;
    int*   cnt       = (int*)(ws + OFF_CNT);
    int*   rowptr    = (int*)(ws + OFF_ROWPTR);
    int*   cursor    = (int*)(ws + OFF_CURSOR);
    int*   part      = (int*)(ws + OFF_PART);
    int*   csr       = (int*)(ws + OFF_CSR);
    float* xl        = ws + OFF_XL;
    float* xr        = ws + OFF_XR;
    float* logit     = ws + OFF_LOGIT;
    float* out       = (float*)d_out;

    // zero cnt only (ws is poisoned 0xAA each call); loop_attr is fully
    // overwritten by loop_gather_kernel.
    hipMemsetAsync(cnt, 0, (size_t)N_NODES * 4, stream);

    hist_cnt_kernel<<<(N_EDGES + 255) / 256, 256, 0, stream>>>(tgt, cnt);
    scanA_kernel<<<SCAN_BLOCKS, 256, 0, stream>>>(cnt, rowptr, part);
    scanB_kernel<<<1, 256, 0, stream>>>(part);
    scanC_kernel<<<SCAN_BLOCKS, 256, 0, stream>>>(rowptr, part, cursor);
    scatter_kernel<<<(EF + 255) / 256, 256, 0, stream>>>(tgt, cursor, csr);
    loop_gather_kernel<<<(N_NODES + 3) / 4, 256, 0, stream>>>(
        ea, csr, rowptr, cnt, loop_attr);

    // conv1 (Fin = 64)
    lin_kernel<64><<<N_NODES / LNT, 128, 0, stream>>>(x, w1l, b1l, w1r, b1r, xl, xr);
    logit_kernel<<<(EF + 4 * EPB - 1) / (4 * EPB), 256, 0, stream>>>(
        xl, xr, ea, loop_attr, src, tgt, w1e, att1, logit);
    node_kernel<<<(N_NODES + 3) / 4, 256, 0, stream>>>(
        xl, logit, csr, rowptr, cnt, src, bias1, out);      // h1 -> d_out

    // conv2 (Fin = 128, input = h1 in d_out)
    lin_kernel<128><<<N_NODES / LNT, 128, 0, stream>>>(out, w2l, b2l, w2r, b2r, xl, xr);
    logit_kernel<<<(EF + 4 * EPB - 1) / (4 * EPB), 256, 0, stream>>>(
        xl, xr, ea, loop_attr, src, tgt, w2e, att2, logit);
    node_kernel<<<(N_NODES + 3) / 4, 256, 0, stream>>>(
        xl, logit, csr, rowptr, cnt, src, bias2, out);      // h2 -> d_out

    // history head, in place on d_out
    hist_kernel<<<N_NODES / LNT, 128, 0, stream>>>(out, hw, hb);
}

// Round 3
// 900.171 us; speedup vs baseline: 1.4384x; 1.4384x over previous
//
#include <hip/hip_runtime.h>
#include <hip/hip_bf16.h>
#include <math.h>

// Problem constants (from reference)
#define N_NODES 50000
#define N_EDGES 800000
#define EF      (N_EDGES + N_NODES)   // edges + self loops = 850000
#define NEG     0.2f

// Workspace layout (in 4-byte words)
#define OFF_LOOP   0          // loop_attr: N*16 floats
#define OFF_CNT    800000     // cnt: N ints (in-degree, real edges only)
#define OFF_ROWPTR 850000     // row_ptr: N ints
#define OFF_CURSOR 900000     // cursor: N ints
#define OFF_PART   950000     // scan partials: 256 ints
#define OFF_CSRSE  950256     // csr_se: EF int2 (src, eid) = 1.7M words
#define OFF_XL     2650256    // xl: N*128 floats
#define OFF_XR     9050256    // xr: N*128 floats
// total = 15,450,256 words = 61.8 MB

#define SCAN_BLOCKS 196       // ceil(50000/256)
#define LNT 8                 // nodes per block in lin/hist kernels

// ---------------------------------------------------------------------------
// In-degree histogram (real edges only). 800k int atomics, L2-resident.
__global__ void hist_cnt_kernel(const int* __restrict__ tgt, int* __restrict__ cnt)
{
    int e = blockIdx.x * 256 + threadIdx.x;
    if (e >= N_EDGES) return;
    atomicAdd(&cnt[tgt[e]], 1);
}

// ---------------------------------------------------------------------------
// CSR build: row_len[n] = cnt[n] + 1 (self loop). 3-kernel exclusive scan.
__global__ void scanA_kernel(const int* __restrict__ cnt, int* __restrict__ rowptr,
                             int* __restrict__ part)
{
    __shared__ int s[256];
    int tid = threadIdx.x;
    int g = blockIdx.x * 256 + tid;
    int v = (g < N_NODES) ? (cnt[g] + 1) : 0;
    s[tid] = v;
    __syncthreads();
    for (int off = 1; off < 256; off <<= 1) {
        int t = (tid >= off) ? s[tid - off] : 0;
        __syncthreads();
        s[tid] += t;
        __syncthreads();
    }
    if (g < N_NODES) rowptr[g] = s[tid] - v;        // block-local exclusive
    if (tid == 255) part[blockIdx.x] = s[255];      // block total
}

__global__ void scanB_kernel(int* __restrict__ part)
{
    __shared__ int s[256];
    int tid = threadIdx.x;
    int v = (tid < SCAN_BLOCKS) ? part[tid] : 0;    // entries >=SCAN_BLOCKS are poison
    s[tid] = v;
    __syncthreads();
    for (int off = 1; off < 256; off <<= 1) {
        int t = (tid >= off) ? s[tid - off] : 0;
        __syncthreads();
        s[tid] += t;
        __syncthreads();
    }
    part[tid] = s[tid] - v;                         // exclusive
}

__global__ void scanC_kernel(int* __restrict__ rowptr, const int* __restrict__ part,
                             int* __restrict__ cursor)
{
    int g = blockIdx.x * 256 + threadIdx.x;
    if (g >= N_NODES) return;
    int r = rowptr[g] + part[blockIdx.x];
    rowptr[g] = r;
    cursor[g] = r;
}

// Scatter edges (and self-loops) into CSR slots as packed (src, eid).
__global__ void scatter_kernel(const int* __restrict__ src, const int* __restrict__ tgt,
                               int* __restrict__ cursor, int2* __restrict__ csr_se)
{
    int e = blockIdx.x * 256 + threadIdx.x;
    if (e >= EF) return;
    int s, t;
    if (e < N_EDGES) { s = src[e]; t = tgt[e]; }
    else             { s = e - N_EDGES; t = s; }
    int pos = atomicAdd(&cursor[t], 1);
    csr_se[pos] = make_int2(s, e);
}

// ---------------------------------------------------------------------------
// Self-loop attr via CSR gather (no float atomics, deterministic):
// loop_attr[n] = mean of ea over incoming real edges. One wave per node,
// 16 lanes = 16 channels, 4 edges in flight.
__global__ __launch_bounds__(256) void loop_gather_kernel(
    const float* __restrict__ ea, const int2* __restrict__ csr_se,
    const int* __restrict__ rowptr, const int* __restrict__ cnt,
    float* __restrict__ loop_attr)
{
    int wave = threadIdx.x >> 6, lane = threadIdx.x & 63;
    int n = blockIdx.x * 4 + wave;
    if (n >= N_NODES) return;
    int base = rowptr[n];
    int degt = cnt[n] + 1;                   // includes the self-loop slot (skipped below)
    int k = lane & 15;
    float acc = 0.f;
    for (int i = lane >> 4; i < degt; i += 4) {
        int eid = csr_se[base + i].y;
        if (eid < N_EDGES) acc += ea[(size_t)eid * 16 + k];
    }
    acc += __shfl_xor(acc, 16);
    acc += __shfl_xor(acc, 32);
    if (lane < 16) {
        int c = cnt[n];
        loop_attr[n * 16 + k] = acc / (float)(c > 0 ? c : 1);
    }
}

// ---------------------------------------------------------------------------
// xl = X@Wl + bl ; xr = X@Wr + br.  128 threads = out channels, LNT nodes/block
// (amortizes weight reads 8x from L2).
template<int K>
__global__ __launch_bounds__(128) void lin_kernel(const float* __restrict__ X,
    const float* __restrict__ Wl, const float* __restrict__ bl,
    const float* __restrict__ Wr, const float* __restrict__ br,
    float* __restrict__ xl, float* __restrict__ xr)
{
    __shared__ float s[LNT][K];
    int j = threadIdx.x;
    int nb = blockIdx.x * LNT;
    for (int t = 0; t < LNT; ++t) {
        int n = nb + t;
        if (n < N_NODES)
            for (int k = j; k < K; k += 128) s[t][k] = X[(size_t)n * K + k];
    }
    __syncthreads();
    float accL[LNT], accR[LNT];
    float blj = bl[j], brj = br[j];
    #pragma unroll
    for (int t = 0; t < LNT; ++t) { accL[t] = blj; accR[t] = brj; }
    for (int k = 0; k < K; ++k) {
        float wl = Wl[k * 128 + j], wr = Wr[k * 128 + j];
        #pragma unroll
        for (int t = 0; t < LNT; ++t) {
            accL[t] = fmaf(s[t][k], wl, accL[t]);
            accR[t] = fmaf(s[t][k], wr, accR[t]);
        }
    }
    for (int t = 0; t < LNT; ++t) {
        int n = nb + t;
        if (n < N_NODES) {
            xl[(size_t)n * 128 + j] = accL[t];
            xr[(size_t)n * 128 + j] = accR[t];
        }
    }
}

// ---------------------------------------------------------------------------
// FUSED logit + edge-softmax + aggregation, one wave per node, online softmax.
// Per edge: xl[src] row is gathered ONCE (512 B) and used for both the logit
// and the weighted accumulation. xr[n] is wave-uniform (loaded once). The
// target of every CSR edge is n itself, so no tgt loads. ea row (64 B) is
// gathered per edge; ee = ea_row @ We computed on the fly (We in LDS).
// 2-deep software pipeline: next edge's loads issue before current compute.
__global__ __launch_bounds__(256) void fused_kernel(
    const float* __restrict__ xl, const float* __restrict__ xr,
    const float* __restrict__ ea, const float* __restrict__ loop_attr,
    const int2* __restrict__ csr_se, const int* __restrict__ rowptr,
    const int* __restrict__ cnt, const float* __restrict__ We,
    const float* __restrict__ att, const float* __restrict__ bias,
    float* __restrict__ out)
{
    __shared__ float sWe[16 * 128];
    __shared__ float sAtt[128];
    int tid = threadIdx.x;
    for (int i = tid; i < 16 * 128; i += 256) sWe[i] = We[i];
    if (tid < 128) sAtt[tid] = att[tid];
    __syncthreads();

    int wave = tid >> 6, lane = tid & 63;
    int n = blockIdx.x * 4 + wave;
    if (n >= N_NODES) return;
    int base = rowptr[n];
    int deg = cnt[n] + 1;                    // + self loop; deg >= 1 always
    int c0 = lane * 2;
    float a0 = sAtt[c0], a1 = sAtt[c0 + 1];
    float2 xrt = *(const float2*)(xr + (size_t)n * 128 + c0);

    float m = -INFINITY, den = 0.f, acc0 = 0.f, acc1 = 0.f;

    // pipeline prologue: load edge 0
    float2 xlv; float eav;
    {
        int2 se = csr_se[base];
        xlv = *(const float2*)(xl + (size_t)se.x * 128 + c0);
        const float* er = (se.y < N_EDGES) ? ea + (size_t)se.y * 16
                                           : loop_attr + (size_t)n * 16;
        eav = er[lane & 15];
    }
    for (int i = 0; i < deg; ++i) {
        float2 xc = xlv; float ec = eav;     // current edge data
        if (i + 1 < deg) {                   // prefetch next edge
            int2 se = csr_se[base + i + 1];
            xlv = *(const float2*)(xl + (size_t)se.x * 128 + c0);
            const float* er = (se.y < N_EDGES) ? ea + (size_t)se.y * 16
                                               : loop_attr + (size_t)n * 16;
            eav = er[lane & 15];
        }
        // ee = ea_row @ We for this lane's 2 channels
        float ee0 = 0.f, ee1 = 0.f;
        #pragma unroll
        for (int k = 0; k < 16; ++k) {
            float ak = __shfl(ec, k, 16);
            ee0 = fmaf(ak, sWe[k * 128 + c0], ee0);
            ee1 = fmaf(ak, sWe[k * 128 + c0 + 1], ee1);
        }
        float m0 = xc.x + xrt.x + ee0; m0 = (m0 > 0.f) ? m0 : NEG * m0;
        float m1 = xc.y + xrt.y + ee1; m1 = (m1 > 0.f) ? m1 : NEG * m1;
        float part = fmaf(m0, a0, m1 * a1);
        part += __shfl_xor(part, 1);         // reduce 16-lane head group
        part += __shfl_xor(part, 2);
        part += __shfl_xor(part, 4);
        part += __shfl_xor(part, 8);
        // online softmax update (per head group; den replicated over 16 lanes)
        float nm = fmaxf(m, part);
        float sc = __expf(m - nm);           // 1 if max unchanged; 0 on first edge
        float w  = __expf(part - nm);
        den  = fmaf(den, sc, w);
        acc0 = fmaf(acc0, sc, w * xc.x);
        acc1 = fmaf(acc1, sc, w * xc.y);
        m = nm;
    }
    float rd = 1.0f / den;
    float o0 = fmaxf(fmaf(acc0, rd, bias[c0]), 0.f);     // + bias, ReLU
    float o1 = fmaxf(fmaf(acc1, rd, bias[c0 + 1]), 0.f);
    *(float2*)(out + (size_t)n * 128 + c0) = make_float2(o0, o1);
}

// ---------------------------------------------------------------------------
// Final head: io = io @ hw + hb, in place (row-disjoint per block => safe).
__global__ __launch_bounds__(128) void hist_kernel(float* __restrict__ io,
    const float* __restrict__ hw, const float* __restrict__ hb)
{
    __shared__ float s[LNT][128];
    int j = threadIdx.x;
    int nb = blockIdx.x * LNT;
    for (int t = 0; t < LNT; ++t) {
        int n = nb + t;
        if (n < N_NODES) s[t][j] = io[(size_t)n * 128 + j];
    }
    __syncthreads();
    float acc[LNT];
    float b = hb[j];
    #pragma unroll
    for (int t = 0; t < LNT; ++t) acc[t] = b;
    for (int k = 0; k < 128; ++k) {
        float w = hw[k * 128 + j];
        #pragma unroll
        for (int t = 0; t < LNT; ++t) acc[t] = fmaf(s[t][k], w, acc[t]);
    }
    for (int t = 0; t < LNT; ++t) {
        int n = nb + t;
        if (n < N_NODES) io[(size_t)n * 128 + j] = acc[t];
    }
}

// ---------------------------------------------------------------------------
extern "C" void kernel_launch(void* const* d_in, const int* in_sizes, int n_in,
                              void* d_out, int out_size, void* d_ws, size_t ws_size,
                              hipStream_t stream)
{
    const float* x    = (const float*)d_in[0];
    const int*   ei   = (const int*)d_in[1];
    const float* ea   = (const float*)d_in[2];
    const float* w1l  = (const float*)d_in[3];
    const float* b1l  = (const float*)d_in[4];
    const float* w1r  = (const float*)d_in[5];
    const float* b1r  = (const float*)d_in[6];
    const float* w1e  = (const float*)d_in[7];
    const float* att1 = (const float*)d_in[8];
    const float* bias1= (const float*)d_in[9];
    const float* w2l  = (const float*)d_in[10];
    const float* b2l  = (const float*)d_in[11];
    const float* w2r  = (const float*)d_in[12];
    const float* b2r  = (const float*)d_in[13];
    const float* w2e  = (const float*)d_in[14];
    const float* att2 = (const float*)d_in[15];
    const float* bias2= (const float*)d_in[16];
    const float* hw   = (const float*)d_in[17];
    const float* hb   = (const float*)d_in[18];
    const int* src = ei;
    const int* tgt = ei + N_EDGES;

    float* ws        = (float*)d_ws;
    float* loop_attr = ws + OFF_LOOP;
    int*   cnt       = (int*)(ws + OFF_CNT);
    int*   rowptr    = (int*)(ws + OFF_ROWPTR);
    int*   cursor    = (int*)(ws + OFF_CURSOR);
    int*   part      = (int*)(ws + OFF_PART);
    int2*  csr_se    = (int2*)(ws + OFF_CSRSE);
    float* xl        = ws + OFF_XL;
    float* xr        = ws + OFF_XR;
    float* out       = (float*)d_out;

    // zero cnt only (ws is poisoned 0xAA each call); everything else is
    // fully overwritten before being read.
    hipMemsetAsync(cnt, 0, (size_t)N_NODES * 4, stream);

    hist_cnt_kernel<<<(N_EDGES + 255) / 256, 256, 0, stream>>>(tgt, cnt);
    scanA_kernel<<<SCAN_BLOCKS, 256, 0, stream>>>(cnt, rowptr, part);
    scanB_kernel<<<1, 256, 0, stream>>>(part);
    scanC_kernel<<<SCAN_BLOCKS, 256, 0, stream>>>(rowptr, part, cursor);
    scatter_kernel<<<(EF + 255) / 256, 256, 0, stream>>>(src, tgt, cursor, csr_se);
    loop_gather_kernel<<<(N_NODES + 3) / 4, 256, 0, stream>>>(
        ea, csr_se, rowptr, cnt, loop_attr);

    // conv1 (Fin = 64)
    lin_kernel<64><<<N_NODES / LNT, 128, 0, stream>>>(x, w1l, b1l, w1r, b1r, xl, xr);
    fused_kernel<<<(N_NODES + 3) / 4, 256, 0, stream>>>(
        xl, xr, ea, loop_attr, csr_se, rowptr, cnt, w1e, att1, bias1, out);

    // conv2 (Fin = 128, input = h1 in d_out)
    lin_kernel<128><<<N_NODES / LNT, 128, 0, stream>>>(out, w2l, b2l, w2r, b2r, xl, xr);
    fused_kernel<<<(N_NODES + 3) / 4, 256, 0, stream>>>(
        xl, xr, ea, loop_attr, csr_se, rowptr, cnt, w2e, att2, bias2, out);

    // history head, in place on d_out
    hist_kernel<<<N_NODES / LNT, 128, 0, stream>>>(out, hw, hb);
}